// Round 2
// baseline (1663.662 us; speedup 1.0000x reference)
//
#include <hip/hip_runtime.h>
#include <hip/hip_bf16.h>

#define BB 64
#define TT 12
#define NN 207
#define DD 128
#define HH 8
#define DH 16
#define MROWS (BB*TT*NN)   // 158976 = 621*256
#define KPAD 224           // graph rows padded to multiple of 32

typedef __bf16 bf16x8 __attribute__((ext_vector_type(8)));
typedef float  f32x4  __attribute__((ext_vector_type(4)));

__device__ inline float  b2f(__bf16 v){ return (float)v; }
__device__ inline __bf16 f2b(float v){ return (__bf16)v; }

// load 8 contiguous elements as a bf16x8 MFMA fragment
__device__ inline bf16x8 ldfrag(const __bf16* p){
    return *reinterpret_cast<const bf16x8*>(p);
}
__device__ inline bf16x8 ldfrag(const float* p){
    f32x4 a = *reinterpret_cast<const f32x4*>(p);
    f32x4 b = *reinterpret_cast<const f32x4*>(p+4);
    bf16x8 r;
    #pragma unroll
    for (int i=0;i<4;i++){ r[i] = f2b(a[i]); r[i+4] = f2b(b[i]); }
    return r;
}

// ---------------- graph pad: gp[t][r][0:224] bf16, zeros beyond 207 ----------------
__global__ void pad_graph_kernel(const float* __restrict__ g, __bf16* __restrict__ gp)
{
    int idx = blockIdx.x*256 + threadIdx.x;
    int total = TT*NN*KPAD;
    if (idx >= total) return;
    int k = idx % KPAD;
    int r = idx / KPAD;          // r = t*207 + row
    gp[idx] = (k < NN) ? f2b(g[(size_t)r*NN + k]) : f2b(0.f);
}

// ---------------- propagate: xs1[b,t] = graph[t] @ x[b,t]  (207x207 @ 207x128) ----------------
__global__ __launch_bounds__(256) void propagate_kernel(const __bf16* __restrict__ gp,
    const float* __restrict__ x, __bf16* __restrict__ xs1)
{
    int bt   = blockIdx.x;          // b*12 + t
    int t    = bt % TT;
    int tile = blockIdx.y;          // 0..3, 64 rows each
    int lane = threadIdx.x & 63, w = threadIdx.x >> 6;
    int lhi = lane >> 4, llo = lane & 15;
    __shared__ __attribute__((aligned(16))) __bf16 XT[DD][40];  // XT[c][k], padded
    const float*  xbt  = x  + (size_t)bt*NN*DD;
    const __bf16* grow = gp + (size_t)t*NN*KPAD;
    int rowbase = tile*64 + w*16;
    f32x4 acc[8];
    #pragma unroll
    for (int i=0;i<8;i++) acc[i] = (f32x4){0.f,0.f,0.f,0.f};
    int arow = rowbase + llo; if (arow > NN-1) arow = NN-1;
    for (int k0=0; k0<KPAD; k0+=32) {
        __syncthreads();
        // stage XT[c][kl] = x[bt][k0+kl][c]  (zero-pad k >= 207)
        for (int kl = (threadIdx.x>>7); kl < 32; kl += 2) {
            int kk = k0 + kl, c = threadIdx.x & 127;
            XT[c][kl] = (kk < NN) ? f2b(xbt[(size_t)kk*DD + c]) : f2b(0.f);
        }
        __syncthreads();
        bf16x8 a = ldfrag(grow + (size_t)arow*KPAD + k0 + lhi*8);
        #pragma unroll
        for (int cf=0;cf<8;cf++){
            bf16x8 b = *reinterpret_cast<const bf16x8*>(&XT[cf*16+llo][lhi*8]);
            acc[cf] = __builtin_amdgcn_mfma_f32_16x16x32_bf16(a, b, acc[cf], 0,0,0);
        }
    }
    #pragma unroll
    for (int e=0;e<4;e++){
        int row = rowbase + lhi*4 + e;
        if (row < NN) {
            #pragma unroll
            for (int cf=0;cf<8;cf++)
                xs1[((size_t)bt*NN + row)*DD + cf*16 + llo] = f2b(acc[cf][e]);
        }
    }
}

// ---------------- generic GEMM: C[m][c] = sum_d A[m][d]*W[c][d] (+bias) ----------------
// A: M x K row-major (f32 or bf16). W: NC x K row-major (f32 or bf16).
// grid.x = M/256, grid.y = NC/128.
// MODE 0: bf16 out (opt RELU). MODE 1: f32 out = v. MODE 2: f32 out += v.
template<int MODE, bool RELU, typename TA, typename TW>
__global__ __launch_bounds__(256) void gemm_kernel(const TA* __restrict__ A,
    const TW* __restrict__ W, const float* __restrict__ bias,
    void* __restrict__ out, int K, int NC)
{
    int w = threadIdx.x >> 6, lane = threadIdx.x & 63;
    int lhi = lane >> 4, llo = lane & 15;
    size_t row0 = (size_t)blockIdx.x*256 + (size_t)w*64;
    int col0 = blockIdx.y*128;
    f32x4 acc[4][8];
    #pragma unroll
    for (int i=0;i<4;i++)
        #pragma unroll
        for (int j=0;j<8;j++) acc[i][j] = (f32x4){0.f,0.f,0.f,0.f};
    for (int k0 = 0; k0 < K; k0 += 32) {
        int ke = k0 + lhi*8;
        bf16x8 a[4], b[8];
        #pragma unroll
        for (int rt=0;rt<4;rt++)
            a[rt] = ldfrag(A + (row0 + rt*16 + llo)*(size_t)K + ke);
        #pragma unroll
        for (int cf=0;cf<8;cf++)
            b[cf] = ldfrag(W + (size_t)(col0 + cf*16 + llo)*K + ke);
        #pragma unroll
        for (int rt=0;rt<4;rt++)
            #pragma unroll
            for (int cf=0;cf<8;cf++)
                acc[rt][cf] = __builtin_amdgcn_mfma_f32_16x16x32_bf16(a[rt], b[cf], acc[rt][cf], 0,0,0);
    }
    float bv[8];
    #pragma unroll
    for (int cf=0;cf<8;cf++) bv[cf] = bias ? bias[col0 + cf*16 + llo] : 0.f;
    #pragma unroll
    for (int rt=0;rt<4;rt++) {
        #pragma unroll
        for (int e=0;e<4;e++) {
            size_t row = row0 + rt*16 + lhi*4 + e;
            #pragma unroll
            for (int cf=0;cf<8;cf++) {
                float v = acc[rt][cf][e] + bv[cf];
                size_t idx = row*NC + col0 + cf*16 + llo;
                if (MODE == 0) {
                    if (RELU) v = fmaxf(v, 0.f);
                    ((__bf16*)out)[idx] = f2b(v);
                } else if (MODE == 1) {
                    ((float*)out)[idx] = v;
                } else {
                    ((float*)out)[idx] += v;
                }
            }
        }
    }
}

// ---------------- linear attention (Performer-style), one block per (sequence, head) ----------------
// qkv: M x 384 bf16 (q cols 0..127, k 128..255, v 256..383), head h -> sub-cols [h*16, h*16+16)
// spatial: seq = (b,t), element n, L=207, out cols [0,128)
// temporal: seq = (b,nn), element t, L=12,  out cols [128,256)
__global__ __launch_bounds__(256) void attn_kernel(const __bf16* __restrict__ qkv,
                                                   __bf16* __restrict__ outST, int temporal)
{
    int h = blockIdx.y;
    size_t base; int rstride, L, outcol;
    if (temporal) {
        int b = blockIdx.x / NN, nn = blockIdx.x % NN;
        base = (size_t)b*TT*NN + nn; rstride = NN; L = TT; outcol = DD;
    } else {
        base = (size_t)blockIdx.x*NN; rstride = 1; L = NN; outcol = 0;
    }
    __shared__ float invq[NN], invk[NN], den[NN];
    __shared__ float kvs[DH][DH+1], ksum[DH];
    int tid = threadIdx.x;
    const __bf16* qb = qkv + h*DH;
    const __bf16* kb = qkv + DD + h*DH;
    const __bf16* vb = qkv + 2*DD + h*DH;

    // phase A: per-element inverse L2 norms of q and k (over the 16 head dims)
    for (int n = tid; n < L; n += 256) {
        size_t r = (base + (size_t)n*rstride)*384;
        float sq = 0.f, sk = 0.f;
        #pragma unroll
        for (int m2=0;m2<DH;m2++){
            float qv = b2f(qb[r+m2]); sq += qv*qv;
            float kv = b2f(kb[r+m2]); sk += kv*kv;
        }
        invq[n] = 1.f/fmaxf(sqrtf(sq), 1e-12f);
        invk[n] = 1.f/fmaxf(sqrtf(sk), 1e-12f);
    }
    __syncthreads();
    // phase B: kvs[m][dd] = sum_n khat[n][m]*v[n][dd];  ksum[m] = sum_n khat[n][m]
    {
        int m = tid & 15, dd = tid >> 4;
        float kv = 0.f, ks = 0.f;
        for (int n=0;n<L;n++){
            size_t r = (base + (size_t)n*rstride)*384;
            float kh = b2f(kb[r+m]) * invk[n];
            kv += kh * b2f(vb[r+dd]);
            ks += kh;
        }
        kvs[m][dd] = kv;
        if (dd == 0) ksum[m] = ks;
    }
    __syncthreads();
    // phase C: den[n] = max(qhat . ksum + L, 1e-5)
    for (int n = tid; n < L; n += 256) {
        size_t r = (base + (size_t)n*rstride)*384;
        float s = 0.f;
        #pragma unroll
        for (int m2=0;m2<DH;m2++) s += b2f(qb[r+m2]) * ksum[m2];
        den[n] = fmaxf(s*invq[n] + (float)L, 1e-5f);
    }
    __syncthreads();
    // phase D: out[n][dd] = (qhat . kvs[:,dd] + L*v[n][dd]) / den[n]
    for (int idx = tid; idx < L*DH; idx += 256) {
        int n = idx >> 4, dd = idx & 15;
        size_t r = (base + (size_t)n*rstride)*384;
        float num = (float)L * b2f(vb[r+dd]);
        float iq = invq[n];
        #pragma unroll
        for (int m2=0;m2<DH;m2++) num += b2f(qb[r+m2]) * iq * kvs[m2][dd];
        outST[(base + (size_t)n*rstride)*256 + outcol + h*DH + dd] = f2b(num/den[n]);
    }
}

// ---------------- LayerNorm: out = LN(xb + add) * g + b ; one wave per 128-col row ----------------
template<typename XT, typename OT>
__global__ __launch_bounds__(256) void ln_kernel(const XT* __restrict__ xb,
    const float* __restrict__ add, const float* __restrict__ g,
    const float* __restrict__ bta, OT* __restrict__ out)
{
    int lane = threadIdx.x & 63, wv = threadIdx.x >> 6;
    size_t m = (size_t)blockIdx.x*4 + wv;
    size_t off = m*DD + (size_t)lane*2;
    float v0 = (float)xb[off]   + add[off];
    float v1 = (float)xb[off+1] + add[off+1];
    float s = v0+v1, ss = v0*v0 + v1*v1;
    #pragma unroll
    for (int o=32;o>0;o>>=1){ s += __shfl_xor(s,o,64); ss += __shfl_xor(ss,o,64); }
    float mean = s * (1.f/DD);
    float var  = ss * (1.f/DD) - mean*mean;
    float rs   = rsqrtf(var + 1e-5f);
    int c = lane*2;
    out[off]   = (OT)((v0-mean)*rs*g[c]   + bta[c]);
    out[off+1] = (OT)((v1-mean)*rs*g[c+1] + bta[c+1]);
}

extern "C" void kernel_launch(void* const* d_in, const int* in_sizes, int n_in,
                              void* d_out, int out_size, void* d_ws, size_t ws_size,
                              hipStream_t stream)
{
    const float* x     = (const float*)d_in[0];
    const float* graph = (const float*)d_in[1];
    const float* qkv_w = (const float*)d_in[2];
    const float* out_w = (const float*)d_in[3];
    const float* out_b = (const float*)d_in[4];
    const float* pw_w  = (const float*)d_in[5];
    const float* pw_b  = (const float*)d_in[6];
    const float* fc1_w = (const float*)d_in[7];
    const float* fc1_b = (const float*)d_in[8];
    const float* fc2_w = (const float*)d_in[9];
    const float* fc2_b = (const float*)d_in[10];
    const float* ln1g  = (const float*)d_in[11];
    const float* ln1b  = (const float*)d_in[12];
    const float* ln2g  = (const float*)d_in[13];
    const float* ln2b  = (const float*)d_in[14];
    (void)in_sizes; (void)n_in; (void)out_size; (void)ws_size;

    char* ws = (char*)d_ws;
    size_t off = 0;
    float*  agg  = (float*)(ws + off);  off += (size_t)MROWS*DD*4;      // f32 residual accumulator / ff2
    __bf16* xs1  = (__bf16*)(ws + off); off += (size_t)MROWS*DD*2;      // propagated x (bf16)
    __bf16* qkvb = (__bf16*)(ws + off); off += (size_t)MROWS*3*DD*2;    // qkv (also ff1 reuse)
    __bf16* stb  = (__bf16*)(ws + off); off += (size_t)MROWS*2*DD*2;    // [out_s | out_t] (also h reuse)
    __bf16* gpad = (__bf16*)(ws + off); off += (size_t)TT*NN*KPAD*2;    // padded graph (bf16)
    __bf16* hbuf = stb;                                                  // reuse after hops done

    dim3 blk(256);

    pad_graph_kernel<<<dim3((TT*NN*KPAD + 255)/256), blk, 0, stream>>>(graph, gpad);
    propagate_kernel<<<dim3(BB*TT, 4), blk, 0, stream>>>(gpad, x, xs1);

    for (int hop = 0; hop < 2; ++hop) {
        // qkv = xs[hop] @ qkv_w[hop]^T  (A dtype differs per hop)
        if (hop == 0)
            gemm_kernel<0,false><<<dim3(MROWS/256, 3), blk, 0, stream>>>(
                x, qkv_w, (const float*)nullptr, (void*)qkvb, DD, 3*DD);
        else
            gemm_kernel<0,false><<<dim3(MROWS/256, 3), blk, 0, stream>>>(
                xs1, qkv_w + (size_t)3*DD*DD, (const float*)nullptr, (void*)qkvb, DD, 3*DD);
        // attention (spatial then temporal) -> stb
        attn_kernel<<<dim3(BB*TT, HH), blk, 0, stream>>>(qkvb, stb, 0);
        attn_kernel<<<dim3(BB*NN, HH), blk, 0, stream>>>(qkvb, stb, 1);
        // pointwise branch into agg (init on hop 0, accumulate on hop 1)
        if (hop == 0)
            gemm_kernel<1,false><<<dim3(MROWS/256, 1), blk, 0, stream>>>(
                x, pw_w, pw_b, (void*)agg, DD, DD);
        else
            gemm_kernel<2,false><<<dim3(MROWS/256, 1), blk, 0, stream>>>(
                xs1, pw_w + (size_t)DD*DD, pw_b + DD, (void*)agg, DD, DD);
        // out-projection of concat(out_s, out_t): agg += stb @ out_w[hop]^T + out_b[hop]
        gemm_kernel<2,false><<<dim3(MROWS/256, 1), blk, 0, stream>>>(
            stb, out_w + (size_t)hop*DD*2*DD, out_b + (size_t)hop*DD, (void*)agg, 2*DD, DD);
    }

    // h = LN(x + agg)   (hbuf aliases stb — stb no longer needed)
    ln_kernel<<<dim3(MROWS/4), blk, 0, stream>>>(x, agg, ln1g, ln1b, hbuf);
    // ff1 = relu(h @ fc1^T + b1)  -> reuse qkvb
    gemm_kernel<0,true><<<dim3(MROWS/256, 2), blk, 0, stream>>>(
        hbuf, fc1_w, fc1_b, (void*)qkvb, DD, 2*DD);
    // ff2 = ff1 @ fc2^T + b2 -> agg (f32)
    gemm_kernel<1,false><<<dim3(MROWS/256, 1), blk, 0, stream>>>(
        qkvb, fc2_w, fc2_b, (void*)agg, 2*DD, DD);
    // out = LN(h + ff2) -> d_out (f32)
    ln_kernel<<<dim3(MROWS/4), blk, 0, stream>>>(hbuf, agg, ln2g, ln2b, (float*)d_out);
}

// Round 4
// 1086.265 us; speedup vs baseline: 1.5315x; 1.5315x over previous
//
#include <hip/hip_runtime.h>
#include <hip/hip_bf16.h>

#define BB 64
#define TT 12
#define NN 207
#define DD 128
#define HH 8
#define DH 16
#define MROWS (BB*TT*NN)   // 158976 = 621*256
#define KPAD 224           // graph rows padded to multiple of 32
#define AW 768             // abuf width: [x | xs1 | s0 | t0 | s1 | t1] each 128
#define CHB 32             // batch chunk for qkv/attention
#define CROWS (CHB*TT*NN)  // 79488 rows per chunk

typedef __bf16 bf16x8 __attribute__((ext_vector_type(8)));
typedef float  f32x4  __attribute__((ext_vector_type(4)));

__device__ inline float  b2f(__bf16 v){ return (float)v; }
__device__ inline __bf16 f2b(float v){ return (__bf16)v; }
__device__ inline bf16x8 ldfrag(const __bf16* p){ return *reinterpret_cast<const bf16x8*>(p); }

// ---------------- x (f32) -> abuf[:,0:128] bf16 ----------------
__global__ __launch_bounds__(256) void xcopy_kernel(const float* __restrict__ x, __bf16* __restrict__ abuf)
{
    int nt = gridDim.x*256;
    for (int gIdx = blockIdx.x*256 + threadIdx.x; gIdx < MROWS*16; gIdx += nt) {
        int row = gIdx >> 4, c8 = (gIdx & 15)*8;
        const float* s = x + (size_t)row*DD + c8;
        f32x4 a = *reinterpret_cast<const f32x4*>(s);
        f32x4 b = *reinterpret_cast<const f32x4*>(s+4);
        bf16x8 r;
        #pragma unroll
        for (int i=0;i<4;i++){ r[i] = f2b(a[i]); r[i+4] = f2b(b[i]); }
        *reinterpret_cast<bf16x8*>(abuf + (size_t)row*AW + c8) = r;
    }
}

// ---------------- misc prep: pad graph + convert weights to bf16 + combined bias ----------------
__global__ __launch_bounds__(256) void prep_misc_kernel(
    const float* __restrict__ graph, const float* __restrict__ qkv_w,
    const float* __restrict__ out_w, const float* __restrict__ out_b,
    const float* __restrict__ pw_w,  const float* __restrict__ pw_b,
    const float* __restrict__ fc1_w, const float* __restrict__ fc2_w,
    __bf16* __restrict__ gpad, __bf16* __restrict__ qkv_wb, __bf16* __restrict__ wcomb,
    __bf16* __restrict__ fc1_wb, __bf16* __restrict__ fc2_wb, float* __restrict__ bias_comb)
{
    int nt = gridDim.x*256;
    int tid = blockIdx.x*256 + threadIdx.x;
    for (int i = tid; i < TT*NN*KPAD; i += nt) {
        int k = i % KPAD, r = i / KPAD;
        gpad[i] = (k < NN) ? f2b(graph[(size_t)r*NN + k]) : f2b(0.f);
    }
    for (int i = tid; i < 2*3*DD*DD; i += nt) qkv_wb[i] = f2b(qkv_w[i]);
    for (int i = tid; i < DD*AW; i += nt) {
        int c = i / AW, j = i % AW;
        float v;
        if      (j < 128) v = pw_w[c*128 + j];
        else if (j < 256) v = pw_w[128*128 + c*128 + (j-128)];
        else if (j < 512) v = out_w[c*256 + (j-256)];
        else              v = out_w[128*256 + c*256 + (j-512)];
        wcomb[i] = f2b(v);
    }
    for (int i = tid; i < 2*DD*DD; i += nt) fc1_wb[i] = f2b(fc1_w[i]);
    for (int i = tid; i < 2*DD*DD; i += nt) fc2_wb[i] = f2b(fc2_w[i]);
    for (int i = tid; i < DD; i += nt)
        bias_comb[i] = pw_b[i] + pw_b[128+i] + out_b[i] + out_b[128+i];
}

// ---------------- propagate: abuf[:,128:256] = graph[t] @ abuf[:,0:128]  per (b,t) ----------------
__global__ __launch_bounds__(256) void propagate_kernel(const __bf16* __restrict__ gp,
    __bf16* __restrict__ abuf)
{
    int bt   = blockIdx.x;          // b*12 + t
    int t    = bt % TT;
    int tile = blockIdx.y;          // 0..3, 64 rows each
    int lane = threadIdx.x & 63, w = threadIdx.x >> 6;
    int lhi = lane >> 4, llo = lane & 15;
    __shared__ __attribute__((aligned(16))) __bf16 XT[DD][40];
    const __bf16* xbt  = abuf + (size_t)bt*NN*AW;     // x cols 0:128
    const __bf16* grow = gp + (size_t)t*NN*KPAD;
    int rowbase = tile*64 + w*16;
    f32x4 acc[8];
    #pragma unroll
    for (int i=0;i<8;i++) acc[i] = (f32x4){0.f,0.f,0.f,0.f};
    int arow = rowbase + llo; if (arow > NN-1) arow = NN-1;
    for (int k0=0; k0<KPAD; k0+=32) {
        __syncthreads();
        for (int kl = (threadIdx.x>>7); kl < 32; kl += 2) {
            int kk = k0 + kl, c = threadIdx.x & 127;
            XT[c][kl] = (kk < NN) ? xbt[(size_t)kk*AW + c] : f2b(0.f);
        }
        __syncthreads();
        bf16x8 a = ldfrag(grow + (size_t)arow*KPAD + k0 + lhi*8);
        #pragma unroll
        for (int cf=0;cf<8;cf++){
            bf16x8 b = *reinterpret_cast<const bf16x8*>(&XT[cf*16+llo][lhi*8]);
            acc[cf] = __builtin_amdgcn_mfma_f32_16x16x32_bf16(a, b, acc[cf], 0,0,0);
        }
    }
    #pragma unroll
    for (int e=0;e<4;e++){
        int row = rowbase + lhi*4 + e;
        if (row < NN) {
            #pragma unroll
            for (int cf=0;cf<8;cf++)
                abuf[((size_t)bt*NN + row)*AW + DD + cf*16 + llo] = f2b(acc[cf][e]);
        }
    }
}

// ---------------- generic GEMM: out[m][c] = sum_d A[m][d]*W[c][d] (+bias) ----------------
// A: bf16, row stride lda, rows clamped to mend. W: bf16 [NC][K] dense. grid: (ceil(M/256), NC/128).
// MODE 0: bf16 out (opt RELU).
// MODE 3: out_bf16[row*ldc+col] = LN(resid_f32[row*128+col] + acc + bias) (grid.y==1, NC=128)
// MODE 4: out_f32 [row*ldc+col] = LN(resid_bf16[row*AW+col]  + acc + bias) (grid.y==1, NC=128)
template<int MODE, bool RELU>
__global__ __launch_bounds__(256) void gemm_kernel(const __bf16* __restrict__ A, size_t lda,
    const __bf16* __restrict__ W, const float* __restrict__ bias,
    void* out, size_t ldc, int K, int mend,
    const void* resid, const float* __restrict__ lng, const float* __restrict__ lnb)
{
    int w = threadIdx.x >> 6, lane = threadIdx.x & 63;
    int lhi = lane >> 4, llo = lane & 15;
    size_t row0 = (size_t)blockIdx.x*256 + (size_t)w*64;
    int col0 = blockIdx.y*128;
    const __bf16* aptr[4];
    #pragma unroll
    for (int rt=0;rt<4;rt++){
        long r = (long)(row0 + rt*16 + llo);
        if (r >= mend) r = mend-1;
        aptr[rt] = A + (size_t)r*lda;
    }
    f32x4 acc[4][8];
    #pragma unroll
    for (int i=0;i<4;i++)
        #pragma unroll
        for (int j=0;j<8;j++) acc[i][j] = (f32x4){0.f,0.f,0.f,0.f};
    for (int k0 = 0; k0 < K; k0 += 32) {
        int ke = k0 + lhi*8;
        bf16x8 a[4], b[8];
        #pragma unroll
        for (int rt=0;rt<4;rt++) a[rt] = ldfrag(aptr[rt] + ke);
        #pragma unroll
        for (int cf=0;cf<8;cf++)
            b[cf] = ldfrag(W + (size_t)(col0 + cf*16 + llo)*K + ke);
        #pragma unroll
        for (int rt=0;rt<4;rt++)
            #pragma unroll
            for (int cf=0;cf<8;cf++)
                acc[rt][cf] = __builtin_amdgcn_mfma_f32_16x16x32_bf16(a[rt], b[cf], acc[rt][cf], 0,0,0);
    }
    float bv[8];
    #pragma unroll
    for (int cf=0;cf<8;cf++) bv[cf] = bias ? bias[col0 + cf*16 + llo] : 0.f;

    if (MODE == 0) {
        #pragma unroll
        for (int rt=0;rt<4;rt++) {
            #pragma unroll
            for (int e=0;e<4;e++) {
                size_t row = row0 + rt*16 + lhi*4 + e;
                if ((long)row >= mend) continue;
                #pragma unroll
                for (int cf=0;cf<8;cf++) {
                    float v = acc[rt][cf][e] + bv[cf];
                    if (RELU) v = fmaxf(v, 0.f);
                    ((__bf16*)out)[row*ldc + col0 + cf*16 + llo] = f2b(v);
                }
            }
        }
    } else {
        // fused LayerNorm epilogue (col0 == 0, full 128 cols in block)
        float g8[8], b8[8];
        #pragma unroll
        for (int cf=0;cf<8;cf++){ int c = cf*16 + llo; g8[cf] = lng[c]; b8[cf] = lnb[c]; }
        #pragma unroll
        for (int rt=0;rt<4;rt++) {
            #pragma unroll
            for (int e=0;e<4;e++) {
                size_t row = row0 + rt*16 + lhi*4 + e;
                if ((long)row >= mend) continue;
                float vals[8], s = 0.f, ss = 0.f;
                #pragma unroll
                for (int cf=0;cf<8;cf++) {
                    int c = cf*16 + llo;
                    float r = (MODE == 3) ? ((const float*)resid)[row*DD + c]
                                          : b2f(((const __bf16*)resid)[row*AW + c]);
                    float v = acc[rt][cf][e] + bv[cf] + r;
                    vals[cf] = v; s += v; ss += v*v;
                }
                #pragma unroll
                for (int o=1;o<16;o<<=1){ s += __shfl_xor(s,o,64); ss += __shfl_xor(ss,o,64); }
                float mean = s * (1.f/DD);
                float var  = ss * (1.f/DD) - mean*mean;
                float rs   = rsqrtf(var + 1e-5f);
                #pragma unroll
                for (int cf=0;cf<8;cf++) {
                    float v = (vals[cf]-mean)*rs*g8[cf] + b8[cf];
                    size_t idx = row*ldc + cf*16 + llo;
                    if (MODE == 3) ((__bf16*)out)[idx] = f2b(v);
                    else           ((float*)out)[idx]  = v;
                }
            }
        }
    }
}

// ---------------- spatial linear attention: one block per chunk-(b,t), all 8 heads ----------------
// qkv: chunk-local [CROWS][384] bf16. outp: abuf region for this chunk+hop (row stride AW).
#define CH 32
__global__ __launch_bounds__(256) void attn_s_kernel(const __bf16* __restrict__ qkv,
                                                     __bf16* __restrict__ outp)
{
    int bt = blockIdx.x;   // chunk-local
    const __bf16* base = qkv + (size_t)bt*NN*384;
    __shared__ __attribute__((aligned(16))) __bf16 rows[CH][392];
    __shared__ float invq[224][8];
    __shared__ float invk_c[CH][8];
    __shared__ float ksum_l[8][16];
    int tid = threadIdx.x;
    int dd = tid & 15, half = (tid >> 4) & 1, h = tid >> 5;
    float kvs_col[16]; float ks = 0.f;
    #pragma unroll
    for (int m=0;m<16;m++) kvs_col[m] = 0.f;

    // ---- pass 1: norms + kvs/ksum ----
    for (int c0 = 0; c0 < NN; c0 += CH) {
        __syncthreads();
        for (int i = tid; i < CH*48; i += 256) {
            int r = i/48, g = i%48; int n = c0 + r;
            bf16x8 v8 = (bf16x8){};
            if (n < NN) v8 = *reinterpret_cast<const bf16x8*>(base + (size_t)n*384 + g*8);
            *reinterpret_cast<bf16x8*>(&rows[r][g*8]) = v8;
        }
        __syncthreads();
        {   // norms: 256 threads = (r, hh)
            int r = tid >> 3, hh = tid & 7;
            bf16x8 q0 = *reinterpret_cast<const bf16x8*>(&rows[r][hh*16]);
            bf16x8 q1 = *reinterpret_cast<const bf16x8*>(&rows[r][hh*16+8]);
            bf16x8 k0 = *reinterpret_cast<const bf16x8*>(&rows[r][128+hh*16]);
            bf16x8 k1 = *reinterpret_cast<const bf16x8*>(&rows[r][128+hh*16+8]);
            float sq = 0.f, sk = 0.f;
            #pragma unroll
            for (int m=0;m<8;m++){
                float a0=b2f(q0[m]), a1=b2f(q1[m]); sq += a0*a0 + a1*a1;
                float c0v=b2f(k0[m]), c1=b2f(k1[m]); sk += c0v*c0v + c1*c1;
            }
            invq[c0+r][hh]   = 1.f/fmaxf(sqrtf(sq), 1e-12f);
            invk_c[r][hh]    = 1.f/fmaxf(sqrtf(sk), 1e-12f);
        }
        __syncthreads();
        #pragma unroll
        for (int i=0;i<CH/2;i++){
            int r = half*(CH/2) + i;
            float iv = invk_c[r][h];
            bf16x8 k0 = *reinterpret_cast<const bf16x8*>(&rows[r][128+h*16]);
            bf16x8 k1 = *reinterpret_cast<const bf16x8*>(&rows[r][128+h*16+8]);
            float vv  = b2f(rows[r][256+h*16+dd]);
            float kdd = b2f(rows[r][128+h*16+dd]);
            float t2 = iv*vv;
            #pragma unroll
            for (int m=0;m<8;m++){
                kvs_col[m]   += b2f(k0[m])*t2;
                kvs_col[m+8] += b2f(k1[m])*t2;
            }
            ks += kdd*iv;
        }
    }
    // ---- half-reduce via lane-bit-4 butterfly ----
    #pragma unroll
    for (int m=0;m<16;m++) kvs_col[m] += __shfl_xor(kvs_col[m], 16, 64);
    ks += __shfl_xor(ks, 16, 64);
    ksum_l[h][dd] = ks;
    __syncthreads();
    float ksr[16];
    #pragma unroll
    for (int m=0;m<16;m++) ksr[m] = ksum_l[h][m];

    // ---- pass 2: den + out ----
    for (int c0 = 0; c0 < NN; c0 += CH) {
        __syncthreads();
        for (int i = tid; i < CH*48; i += 256) {
            int r = i/48, g = i%48; int n = c0 + r;
            bf16x8 v8 = (bf16x8){};
            if (n < NN) v8 = *reinterpret_cast<const bf16x8*>(base + (size_t)n*384 + g*8);
            *reinterpret_cast<bf16x8*>(&rows[r][g*8]) = v8;
        }
        __syncthreads();
        #pragma unroll
        for (int i=0;i<CH/2;i++){
            int r = half*(CH/2) + i; int n = c0 + r;
            if (n >= NN) continue;
            float iq = invq[n][h];
            bf16x8 q0 = *reinterpret_cast<const bf16x8*>(&rows[r][h*16]);
            bf16x8 q1 = *reinterpret_cast<const bf16x8*>(&rows[r][h*16+8]);
            float num = 0.f, den = 0.f;
            #pragma unroll
            for (int m=0;m<8;m++){
                float qm0 = b2f(q0[m]), qm1 = b2f(q1[m]);
                num += qm0*kvs_col[m] + qm1*kvs_col[m+8];
                den += qm0*ksr[m]     + qm1*ksr[m+8];
            }
            float vv = b2f(rows[r][256+h*16+dd]);
            float o = (num*iq + (float)NN*vv) / fmaxf(den*iq + (float)NN, 1e-5f);
            outp[((size_t)bt*NN + n)*AW + h*16 + dd] = f2b(o);
        }
    }
}

// ---------------- temporal linear attention: one block per chunk-(b, nn-pair) ----------------
__global__ __launch_bounds__(256) void attn_t_kernel(const __bf16* __restrict__ qkv,
                                                     __bf16* __restrict__ outp)
{
    int b = blockIdx.x;    // chunk-local
    int nn0 = blockIdx.y * 2;
    __shared__ __attribute__((aligned(16))) __bf16 rows[TT][2][384];
    __shared__ float invq[2][TT][8], invk2[2][TT][8];
    int tid = threadIdx.x;
    for (int i = tid; i < TT*2*48; i += 256) {
        int t = i / 96, rem = i % 96;
        int nl = rem / 48, g = rem % 48;
        int nn = nn0 + nl;
        bf16x8 v8 = (bf16x8){};
        if (nn < NN) v8 = *reinterpret_cast<const bf16x8*>(qkv + ((size_t)(b*TT+t)*NN + nn)*384 + g*8);
        *reinterpret_cast<bf16x8*>(&rows[t][nl][g*8]) = v8;
    }
    __syncthreads();
    if (tid < 192) {
        int hh = tid & 7, t = (tid >> 3) % TT, nl = tid / 96;
        bf16x8 q0 = *reinterpret_cast<const bf16x8*>(&rows[t][nl][hh*16]);
        bf16x8 q1 = *reinterpret_cast<const bf16x8*>(&rows[t][nl][hh*16+8]);
        bf16x8 k0 = *reinterpret_cast<const bf16x8*>(&rows[t][nl][128+hh*16]);
        bf16x8 k1 = *reinterpret_cast<const bf16x8*>(&rows[t][nl][128+hh*16+8]);
        float sq = 0.f, sk = 0.f;
        #pragma unroll
        for (int m=0;m<8;m++){
            float a0=b2f(q0[m]), a1=b2f(q1[m]); sq += a0*a0 + a1*a1;
            float c0v=b2f(k0[m]), c1=b2f(k1[m]); sk += c0v*c0v + c1*c1;
        }
        invq[nl][t][hh]  = 1.f/fmaxf(sqrtf(sq), 1e-12f);
        invk2[nl][t][hh] = 1.f/fmaxf(sqrtf(sk), 1e-12f);
    }
    __syncthreads();
    int dd = tid & 15, h = (tid >> 4) & 7, nl = tid >> 7;
    int nn = nn0 + nl;
    float kvs_col[16], ksum[16];
    #pragma unroll
    for (int m=0;m<16;m++){ kvs_col[m]=0.f; ksum[m]=0.f; }
    #pragma unroll
    for (int t=0;t<TT;t++){
        float iv = invk2[nl][t][h];
        bf16x8 k0 = *reinterpret_cast<const bf16x8*>(&rows[t][nl][128+h*16]);
        bf16x8 k1 = *reinterpret_cast<const bf16x8*>(&rows[t][nl][128+h*16+8]);
        float vv = b2f(rows[t][nl][256+h*16+dd]);
        float t2 = iv*vv;
        #pragma unroll
        for (int m=0;m<8;m++){
            float km0 = b2f(k0[m]), km1 = b2f(k1[m]);
            kvs_col[m]   += km0*t2;  ksum[m]   += km0*iv;
            kvs_col[m+8] += km1*t2;  ksum[m+8] += km1*iv;
        }
    }
    #pragma unroll
    for (int t=0;t<TT;t++){
        float iq = invq[nl][t][h];
        bf16x8 q0 = *reinterpret_cast<const bf16x8*>(&rows[t][nl][h*16]);
        bf16x8 q1 = *reinterpret_cast<const bf16x8*>(&rows[t][nl][h*16+8]);
        float num = 0.f, den = 0.f;
        #pragma unroll
        for (int m=0;m<8;m++){
            float qm0 = b2f(q0[m]), qm1 = b2f(q1[m]);
            num += qm0*kvs_col[m]  + qm1*kvs_col[m+8];
            den += qm0*ksum[m]     + qm1*ksum[m+8];
        }
        float vv = b2f(rows[t][nl][256+h*16+dd]);
        float o = (num*iq + (float)TT*vv) / fmaxf(den*iq + (float)TT, 1e-5f);
        if (nn < NN)
            outp[((size_t)(b*TT+t)*NN + nn)*AW + h*16 + dd] = f2b(o);
    }
}

extern "C" void kernel_launch(void* const* d_in, const int* in_sizes, int n_in,
                              void* d_out, int out_size, void* d_ws, size_t ws_size,
                              hipStream_t stream)
{
    const float* x     = (const float*)d_in[0];
    const float* graph = (const float*)d_in[1];
    const float* qkv_w = (const float*)d_in[2];
    const float* out_w = (const float*)d_in[3];
    const float* out_b = (const float*)d_in[4];
    const float* pw_w  = (const float*)d_in[5];
    const float* pw_b  = (const float*)d_in[6];
    const float* fc1_w = (const float*)d_in[7];
    const float* fc1_b = (const float*)d_in[8];
    const float* fc2_w = (const float*)d_in[9];
    const float* fc2_b = (const float*)d_in[10];
    const float* ln1g  = (const float*)d_in[11];
    const float* ln1b  = (const float*)d_in[12];
    const float* ln2g  = (const float*)d_in[13];
    const float* ln2b  = (const float*)d_in[14];
    (void)in_sizes; (void)n_in; (void)out_size; (void)ws_size;

    char* ws = (char*)d_ws;
    size_t off = 0;
    __bf16* abuf = (__bf16*)(ws + off); off += (size_t)MROWS*AW*2;      // 244.2 MB
    __bf16* qkvc = (__bf16*)(ws + off); off += (size_t)CROWS*3*DD*2;    // 61.0 MB
    __bf16* gpad = (__bf16*)(ws + off); off += (size_t)TT*NN*KPAD*2;    // 1.1 MB
    __bf16* qkv_wb = (__bf16*)(ws + off); off += (size_t)2*3*DD*DD*2;
    __bf16* wcomb  = (__bf16*)(ws + off); off += (size_t)DD*AW*2;
    __bf16* fc1_wb = (__bf16*)(ws + off); off += (size_t)2*DD*DD*2;
    __bf16* fc2_wb = (__bf16*)(ws + off); off += (size_t)2*DD*DD*2;
    float*  bias_comb = (float*)(ws + off); off += DD*4;                // total ~293 MB

    dim3 blk(256);

    xcopy_kernel<<<dim3(4096), blk, 0, stream>>>(x, abuf);
    prep_misc_kernel<<<dim3(1024), blk, 0, stream>>>(graph, qkv_w, out_w, out_b, pw_w, pw_b,
        fc1_w, fc2_w, gpad, qkv_wb, wcomb, fc1_wb, fc2_wb, bias_comb);
    propagate_kernel<<<dim3(BB*TT, 4), blk, 0, stream>>>(gpad, abuf);

    for (int hop = 0; hop < 2; ++hop) {
        for (int c = 0; c < BB/CHB; ++c) {
            size_t rowoff = (size_t)c*CROWS;
            // qkv (chunk) = abuf[rows, hop*128:hop*128+128] @ qkv_w[hop]^T
            gemm_kernel<0,false><<<dim3((CROWS+255)/256, 3), blk, 0, stream>>>(
                abuf + rowoff*AW + hop*DD, (size_t)AW, qkv_wb + (size_t)hop*3*DD*DD, nullptr,
                (void*)qkvc, (size_t)(3*DD), DD, CROWS, nullptr, nullptr, nullptr);
            attn_s_kernel<<<dim3(CHB*TT), blk, 0, stream>>>(
                qkvc, abuf + rowoff*AW + 256 + hop*256);
            attn_t_kernel<<<dim3(CHB, (NN+1)/2), blk, 0, stream>>>(
                qkvc, abuf + rowoff*AW + 384 + hop*256);
        }
    }

    // h = LN(x + abuf@wcomb^T + bias_comb) -> abuf cols 0:128 (bf16), fused epilogue
    gemm_kernel<3,false><<<dim3(MROWS/256, 1), blk, 0, stream>>>(
        abuf, (size_t)AW, wcomb, bias_comb, (void*)abuf, (size_t)AW, AW, MROWS,
        (const void*)x, ln1g, ln1b);
    // ff1 = relu(h @ fc1^T + b1) -> abuf cols 256:512
    gemm_kernel<0,true><<<dim3(MROWS/256, 2), blk, 0, stream>>>(
        abuf, (size_t)AW, fc1_wb, fc1_b, (void*)(abuf + 256), (size_t)AW, DD, MROWS,
        nullptr, nullptr, nullptr);
    // out = LN(h + ff1 @ fc2^T + b2) -> d_out f32, fused epilogue
    gemm_kernel<4,false><<<dim3(MROWS/256, 1), blk, 0, stream>>>(
        abuf + 256, (size_t)AW, fc2_wb, fc2_b, d_out, (size_t)DD, 2*DD, MROWS,
        (const void*)abuf, ln2g, ln2b);
}